// Round 3
// baseline (214.156 us; speedup 1.0000x reference)
//
#include <hip/hip_runtime.h>
#include <hip/hip_bf16.h>
#include <stdint.h>

#define AS1 __attribute__((address_space(1)))
#define AS3 __attribute__((address_space(3)))

typedef __attribute__((ext_vector_type(8))) short short8;
typedef __attribute__((ext_vector_type(4))) float f32x4;
typedef __attribute__((ext_vector_type(4))) int i32x4;

__device__ __forceinline__ unsigned short f2bf(float f) {
  return __builtin_bit_cast(unsigned short, __float2bfloat16(f));
}

// ---------------------------------------------------------------------------
// Kernel 1 (fused quant prep): one block per matrix row.
// Blocks [0, wrows): FWHT-128 on W row (fp32, in-register) -> row absmax ->
//   i8 quantize -> Wq, s_w[row].
// Blocks [wrows, ...): x row absmax -> i8 quantize -> Xq, s_x[row].
// 256 thr x 16 elems = 4096 elems/row. Exact per-row absmax => no clipping;
// error is pure rounding (~0.9% rms per element).
// ---------------------------------------------------------------------------
__global__ __launch_bounds__(256) void quant_prep(const float* __restrict__ W,
                                                  signed char* __restrict__ Wq,
                                                  float* __restrict__ sw,
                                                  const float* __restrict__ x,
                                                  signed char* __restrict__ Xq,
                                                  float* __restrict__ sx,
                                                  int wrows, int Kd) {
  __shared__ float red[4];
  const int bid = blockIdx.x;
  const int tid = threadIdx.x;
  const bool isW = bid < wrows;
  const int row = isW ? bid : bid - wrows;
  const float* src = (isW ? W : x) + (size_t)row * Kd + tid * 16;

  float v[16];
  {
    float4 f0 = ((const float4*)src)[0];
    float4 f1 = ((const float4*)src)[1];
    float4 f2 = ((const float4*)src)[2];
    float4 f3 = ((const float4*)src)[3];
    v[0] = f0.x; v[1] = f0.y; v[2] = f0.z; v[3] = f0.w;
    v[4] = f1.x; v[5] = f1.y; v[6] = f1.z; v[7] = f1.w;
    v[8] = f2.x; v[9] = f2.y; v[10] = f2.z; v[11] = f2.w;
    v[12] = f3.x; v[13] = f3.y; v[14] = f3.z; v[15] = f3.w;
  }

  if (isW) {
    // FWHT-128: thread holds 16 contiguous elems (bits 0..3); a 128-segment
    // spans 8 threads (bits 4..6 = tid&7), all within one wave.
#pragma unroll
    for (int m = 1; m <= 8; m <<= 1) {
#pragma unroll
      for (int j = 0; j < 16; ++j) {
        if ((j & m) == 0) {
          float lo = v[j], hi = v[j + m];
          v[j] = lo + hi;
          v[j + m] = lo - hi;
        }
      }
    }
    const int g = tid & 7;
#pragma unroll
    for (int m = 1; m <= 4; m <<= 1) {
#pragma unroll
      for (int j = 0; j < 16; ++j) {
        float p = __shfl_xor(v[j], m, 64);
        v[j] = (g & m) ? (p - v[j]) : (v[j] + p);
      }
    }
    const float s = 0.08838834764831845f; // 1/sqrt(128)
#pragma unroll
    for (int j = 0; j < 16; ++j) v[j] *= s;
  }

  // row absmax: wave reduce then block reduce (4 waves)
  float am = 0.f;
#pragma unroll
  for (int j = 0; j < 16; ++j) am = fmaxf(am, fabsf(v[j]));
#pragma unroll
  for (int m = 1; m < 64; m <<= 1) am = fmaxf(am, __shfl_xor(am, m, 64));
  if ((tid & 63) == 0) red[tid >> 6] = am;
  __syncthreads();
  am = fmaxf(fmaxf(red[0], red[1]), fmaxf(red[2], red[3]));

  const float inv = (am > 1e-30f) ? (127.0f / am) : 0.f;
  union { uint4 u; signed char c[16]; } pk;
#pragma unroll
  for (int j = 0; j < 16; ++j) {
    float q = __builtin_rintf(v[j] * inv);
    q = fminf(127.f, fmaxf(-127.f, q));
    pk.c[j] = (signed char)(int)q;
  }
  signed char* dst = (isW ? Wq : Xq) + (size_t)row * Kd + tid * 16;
  *(uint4*)dst = pk.u;
  if (tid == 0) (isW ? sw : sx)[row] = am / 127.0f;
}

// ---------------------------------------------------------------------------
__device__ __forceinline__ void gload16(const void* g, void* l) {
  __builtin_amdgcn_global_load_lds((const AS1 unsigned int*)g,
                                   (AS3 unsigned int*)l, 16, 0, 0);
}

// ---------------------------------------------------------------------------
// Kernel 2: i8 GEMM, 2 blocks/CU, m201-style two-barrier phase (R-B-M-B).
//
// R2 post-mortem (per-SIMD arithmetic): per CU-phase, LDS = 128 ds_read_b128
// ~= 1536 cyc (CU-serial) and MFMA = 4 waves/SIMD x 16 x 20.4 ~= 1306 cyc
// (SIMD-parallel); measured phase = 2920 cyc = FULLY SERIALIZED. Counted-lgkm
// was null because the barrier sat between MFMA and the next reads (R-M-B):
// no wave may issue phase-t+1 reads until all waves finish phase-t MFMAs --
// a structural convoy no wait-counting can break.
//
// Fix = m201's barrier placement (R-B1-M-B2): B1 sits BETWEEN reads and
// MFMAs; after its MFMA cluster each wave immediately issues the next phase's
// ds_reads (no barrier in between), so read issue overlaps other waves' MFMA
// drain and the B1 wait absorbs LDS latency (lgkmcnt(0) after B1 is usually
// already satisfied). B2 (after MFMA, preceded by vmcnt(3)) doubles as the
// publish point for tile t+1 AND the read-drain fence that makes restaging
// slot t+2 safe (every wave's reads of that slot drained at its own lgkm(0)
// before B2).
//
// Geometry (unchanged): BM=128, BN=256, 8 waves of 64x64, BK=64, 3-slot LDS
// ring (72 KiB) => 2 blocks/CU. XOR involution on both pre-swizzled global
// stage sources and ds_read offsets (rule #21; 0 bank conflicts measured).
// vmcnt ledger: 3 loads/phase; at the pre-B2 wait outstanding = {S(t+1):3,
// S(t+2):3} -> vmcnt(3) drains exactly S(t+1); never 0 in the loop.
// Dequant epilogue: out = sx[m]*sw[n]*acc + b[n] (integer accum is exact).
// ---------------------------------------------------------------------------
#define BM2 128
#define BN2 256
#define SLOTSZ 24576 // A plane 8192 B (128 rows x 64) + B plane 16384 B (256 rows x 64)

__global__ __launch_bounds__(512, 4) void gemm_i8_2blk(const signed char* __restrict__ Xq,
                                                       const signed char* __restrict__ Wq,
                                                       const float* __restrict__ sx,
                                                       const float* __restrict__ sw,
                                                       const float* __restrict__ bias,
                                                       float* __restrict__ out,
                                                       int M, int N, int K) {
  __shared__ __align__(16) char lds[3 * SLOTSZ];

  const int tid = threadIdx.x;
  const int lane = tid & 63;
  const int wid = tid >> 6; // 0..7
  const int wm = wid >> 2;  // 0..1  (64-row strip)
  const int wn = wid & 3;   // 0..3  (64-col strip)

  // XCD bijective swizzle (gridDim.x = 1024, multiple of 8)
  const int nwg = gridDim.x;
  const int cpx = nwg >> 3;
  const int swzb = (blockIdx.x & 7) * cpx + (blockIdx.x >> 3);
  const int nbn = N / BN2;
  const int m0 = (swzb / nbn) * BM2;
  const int n0 = (swzb % nbn) * BN2;
  const size_t Kb = (size_t)K; // 1 byte/elem

  // ---- stage source pointers: pre-swizzled global (rule #21) ----
  const int dA = tid * 16;         // A plane-relative [0, 8192)
  const int dB0 = tid * 16;        // B plane-relative [0, 8192)
  const int dB1 = tid * 16 + 8192; // B plane-relative [8192, 16384)
  const char* srcA;
  const char* srcB0;
  const char* srcB1;
  {
    int l = dA ^ (((dA >> 7) & 3) << 4);
    srcA = (const char*)Xq + (size_t)(m0 + (l >> 6)) * Kb + (l & 63);
    l = dB0 ^ (((dB0 >> 7) & 3) << 4);
    srcB0 = (const char*)Wq + (size_t)(n0 + (l >> 6)) * Kb + (l & 63);
    l = dB1 ^ (((dB1 >> 7) & 3) << 4);
    srcB1 = (const char*)Wq + (size_t)(n0 + (l >> 6)) * Kb + (l & 63);
  }

  // ---- swizzled in-plane ds_read offsets (same involution) ----
  const int q = lane >> 4;  // k-chunk 0..3 (16 B each = 16 i8)
  const int fr = lane & 15; // frag row
  int oA[4], oB[4];
#pragma unroll
  for (int mi = 0; mi < 4; ++mi) {
    int row = wm * 64 + mi * 16 + fr; // 0..127
    int byt = row * 64 + q * 16;
    oA[mi] = byt ^ (((byt >> 7) & 3) << 4);
  }
#pragma unroll
  for (int ni = 0; ni < 4; ++ni) {
    int row = wn * 64 + ni * 16 + fr; // 0..255
    int byt = row * 64 + q * 16;
    oB[ni] = 8192 + (byt ^ (((byt >> 7) & 3) << 4)); // +8192 = B plane base
  }

  i32x4 acc[4][4];
#pragma unroll
  for (int i = 0; i < 4; ++i)
#pragma unroll
    for (int j = 0; j < 4; ++j) acc[i][j] = (i32x4){0, 0, 0, 0};

#define STAGE3(sl_, ko_)                                                     \
  do {                                                                       \
    gload16(srcA + (ko_), (sl_) + dA);                                       \
    gload16(srcB0 + (ko_), (sl_) + 8192 + dB0);                              \
    gload16(srcB1 + (ko_), (sl_) + 8192 + dB1);                              \
  } while (0)

#define LGKM(n_)                                                             \
  asm volatile("s_waitcnt lgkmcnt(" #n_ ")" ::: "memory");                   \
  __builtin_amdgcn_sched_barrier(0)

#define MFMA1(mi_, ni_, a_, b_)                                              \
  acc[mi_][ni_] = __builtin_amdgcn_mfma_i32_16x16x64_i8(a_, b_, acc[mi_][ni_], 0, 0, 0)

  // ---- prologue: tile0 -> slot0, tile1 -> slot1; publish tile0 ----
  STAGE3(lds, 0);
  STAGE3(lds + SLOTSZ, 64);
  asm volatile("s_waitcnt vmcnt(3)" ::: "memory"); // tile0 landed (tile1 in flight)
  __builtin_amdgcn_s_barrier();
  asm volatile("" ::: "memory");

  char* s0 = lds;              // holds tile t   (published)
  char* s1 = lds + SLOTSZ;     // holds tile t+1 (in flight / landing)
  char* s2 = lds + 2 * SLOTSZ; // dead (tile t-1) -> stage target for t+2
  int koff = 128;              // byte offset along K of tile t+2
  const int NT = K >> 6;       // 64

  for (int t = 0; t < NT; ++t) {
    // ---- R: issue reads for tile t (immediately after B2 of t-1; overlaps
    // other waves' phase t-1 MFMA drain across the CU) ----
    i32x4 av0 = *(const i32x4*)(s0 + oA[0]);
    i32x4 av1 = *(const i32x4*)(s0 + oA[1]);
    i32x4 av2 = *(const i32x4*)(s0 + oA[2]);
    i32x4 av3 = *(const i32x4*)(s0 + oA[3]);
    i32x4 bv0 = *(const i32x4*)(s0 + oB[0]);
    i32x4 bv1 = *(const i32x4*)(s0 + oB[1]);
    i32x4 bv2 = *(const i32x4*)(s0 + oB[2]);
    i32x4 bv3 = *(const i32x4*)(s0 + oB[3]);
    STAGE3(s2, koff); // issue tile t+2 (slot drained by all waves at B2(t-1))
    koff += 64;
    if (koff >= K) koff -= K; // ring wrap: tail phases harmlessly re-stage t0/t1

    // ---- B1: barrier between reads and MFMAs (the overlap enabler) ----
    __builtin_amdgcn_s_barrier();
    asm volatile("" ::: "memory");
    LGKM(0); // own reads issued pre-B1: barrier wait has absorbed the latency

    // ---- M: MFMA cluster ----
    __builtin_amdgcn_s_setprio(1);
    MFMA1(0, 0, av0, bv0);
    MFMA1(0, 1, av0, bv1);
    MFMA1(1, 0, av1, bv0);
    MFMA1(1, 1, av1, bv1);
    MFMA1(0, 2, av0, bv2);
    MFMA1(0, 3, av0, bv3);
    MFMA1(1, 2, av1, bv2);
    MFMA1(1, 3, av1, bv3);
    MFMA1(2, 0, av2, bv0);
    MFMA1(2, 1, av2, bv1);
    MFMA1(3, 0, av3, bv0);
    MFMA1(3, 1, av3, bv1);
    MFMA1(2, 2, av2, bv2);
    MFMA1(2, 3, av2, bv3);
    MFMA1(3, 2, av3, bv2);
    MFMA1(3, 3, av3, bv3);
    __builtin_amdgcn_s_setprio(0);
    __builtin_amdgcn_sched_barrier(0);

    // ---- vmcnt(3)+B2: publish tile t+1 (staged in phase t-1; outstanding
    // here = {S(t+1):3, S(t+2):3}); B2 also fences this phase's slot reads
    // (drained at each wave's LGKM(0)) ahead of next phase's restage. ----
    asm volatile("s_waitcnt vmcnt(3)" ::: "memory");
    __builtin_amdgcn_s_barrier();
    asm volatile("" ::: "memory");

    char* tp = s0; s0 = s1; s1 = s2; s2 = tp;
  }
  asm volatile("s_waitcnt vmcnt(0)" ::: "memory"); // drain wrapped ring stages

  // ---- epilogue: C/D col=lane&15, row=(lane>>4)*4+r (dtype-independent);
  // dequant out = sx[row]*sw[col]*acc + b[col], fp32 store.
  const int orow = m0 + wm * 64;
  const int ocol = n0 + wn * 64;
  const int rsub = q << 2;
#pragma unroll
  for (int ni = 0; ni < 4; ++ni) {
    const int col = ocol + ni * 16 + fr;
    const float swc = sw[col];
    const float bc = bias[col];
#pragma unroll
    for (int mi = 0; mi < 4; ++mi) {
      const int rbase = orow + mi * 16 + rsub;
#pragma unroll
      for (int r = 0; r < 4; ++r) {
        const int row = rbase + r;
        out[(size_t)row * N + col] =
            (float)acc[mi][ni][r] * (sx[row] * swc) + bc;
      }
    }
  }
#undef STAGE3
#undef LGKM
#undef MFMA1
}

// ---------------------------------------------------------------------------
// Fallback (small workspace): bf16 path — standalone FWHT + 128^2 GEMM.
// ---------------------------------------------------------------------------
__global__ __launch_bounds__(256) void fwht_only(const float* __restrict__ W,
                                                 unsigned short* __restrict__ Wp,
                                                 int total_vec) {
  int t = blockIdx.x * blockDim.x + threadIdx.x;
  if (t >= total_vec) return;
  float4 r0 = ((const float4*)W)[2 * t];
  float4 r1 = ((const float4*)W)[2 * t + 1];
  float v[8] = {r0.x, r0.y, r0.z, r0.w, r1.x, r1.y, r1.z, r1.w};
#pragma unroll
  for (int m = 1; m <= 4; m <<= 1) {
#pragma unroll
    for (int j = 0; j < 8; ++j) {
      if ((j & m) == 0) {
        float lo = v[j], hi = v[j + m];
        v[j] = lo + hi;
        v[j + m] = lo - hi;
      }
    }
  }
  const int g = t & 15;
#pragma unroll
  for (int m = 1; m <= 8; m <<= 1) {
#pragma unroll
    for (int j = 0; j < 8; ++j) {
      float p = __shfl_xor(v[j], m, 64);
      v[j] = (g & m) ? (p - v[j]) : (v[j] + p);
    }
  }
  const float s = 0.08838834764831845f;
  uint4 outv;
  unsigned short* ou = (unsigned short*)&outv;
#pragma unroll
  for (int j = 0; j < 8; ++j) ou[j] = f2bf(v[j] * s);
  ((uint4*)Wp)[t] = outv;
}

__global__ __launch_bounds__(256) void gemm128_a32(const float* __restrict__ X,
                                                   const unsigned short* __restrict__ Wp,
                                                   const float* __restrict__ bias,
                                                   float* __restrict__ out,
                                                   int M, int N, int K) {
  __shared__ __align__(16) unsigned short lA[128 * 32];
  __shared__ __align__(16) unsigned short lB[128 * 32];
  const int tid = threadIdx.x;
  const int lane = tid & 63;
  const int wid = tid >> 6;
  const int wr = wid >> 1, wc = wid & 1;
  const int nbn = N / 128;
  const int bm = blockIdx.x / nbn, bn = blockIdx.x % nbn;
  const int m0 = bm * 128, n0 = bn * 128;
  f32x4 acc[4][4];
#pragma unroll
  for (int i = 0; i < 4; ++i)
#pragma unroll
    for (int j = 0; j < 4; ++j) acc[i][j] = (f32x4){0.f, 0.f, 0.f, 0.f};
  const size_t Kb = (size_t)K * 2;
  const int off0 = tid * 16, off1 = off0 + 4096;
  const int r0 = off0 >> 6, c0 = off0 & 63;
  const int r1 = off1 >> 6, c1 = off1 & 63;
  const char* Bg0 = (const char*)Wp + (size_t)(n0 + r0) * Kb + c0;
  const char* Bg1 = (const char*)Wp + (size_t)(n0 + r1) * Kb + c1;
  char* lB0 = (char*)lB + off0;
  char* lB1 = (char*)lB + off1;
  const int arow = tid >> 1;
  const int acol = (tid & 1) * 16;
  const float* Af = X + (size_t)(m0 + arow) * K + acol;
  unsigned short* lAw = &lA[arow * 32 + acol];
  const int fr = lane & 15;
  const int kc = (lane >> 4) << 3;
  const unsigned short* pA = &lA[(wr * 64 + fr) * 32 + kc];
  const unsigned short* pB = &lB[(wc * 64 + fr) * 32 + kc];
  for (int k0 = 0; k0 < K; k0 += 32) {
    const int kb = k0 << 1;
    gload16(Bg0 + kb, lB0);
    gload16(Bg1 + kb, lB1);
    const float* src = Af + k0;
    float4 f0 = *(const float4*)(src + 0);
    float4 f1 = *(const float4*)(src + 4);
    float4 f2 = *(const float4*)(src + 8);
    float4 f3 = *(const float4*)(src + 12);
    union { uint4 u[2]; unsigned short s[16]; } pk;
    float vv[16] = {f0.x, f0.y, f0.z, f0.w, f1.x, f1.y, f1.z, f1.w,
                    f2.x, f2.y, f2.z, f2.w, f3.x, f3.y, f3.z, f3.w};
#pragma unroll
    for (int j = 0; j < 16; ++j) pk.s[j] = f2bf(vv[j]);
    ((uint4*)lAw)[0] = pk.u[0];
    ((uint4*)(lAw + 8))[0] = pk.u[1];
    __syncthreads();
    short8 af[4], bfr[4];
#pragma unroll
    for (int mi = 0; mi < 4; ++mi) af[mi] = *(const short8*)(pA + mi * 16 * 32);
#pragma unroll
    for (int ni = 0; ni < 4; ++ni) bfr[ni] = *(const short8*)(pB + ni * 16 * 32);
#pragma unroll
    for (int mi = 0; mi < 4; ++mi)
#pragma unroll
      for (int ni = 0; ni < 4; ++ni)
        acc[mi][ni] = __builtin_amdgcn_mfma_f32_16x16x32_bf16(af[mi], bfr[ni],
                                                              acc[mi][ni], 0, 0, 0);
    __syncthreads();
  }
  const int orow0 = m0 + wr * 64;
  const int ocol0 = n0 + wc * 64;
  const int rsub = (lane >> 4) << 2;
#pragma unroll
  for (int ni = 0; ni < 4; ++ni) {
    const int col = ocol0 + ni * 16 + fr;
    const float bc = bias[col];
#pragma unroll
    for (int mi = 0; mi < 4; ++mi)
#pragma unroll
      for (int r = 0; r < 4; ++r)
        out[(size_t)(orow0 + mi * 16 + rsub + r) * N + col] = acc[mi][ni][r] + bc;
  }
}

// ---------------------------------------------------------------------------
extern "C" void kernel_launch(void* const* d_in, const int* in_sizes, int n_in,
                              void* d_out, int out_size, void* d_ws, size_t ws_size,
                              hipStream_t stream) {
  const float* x = (const float*)d_in[0];
  const float* W = (const float*)d_in[1];
  const float* b = (const float*)d_in[2];
  float* out = (float*)d_out;

  const int O = in_sizes[2];     // 4096
  const int K = in_sizes[1] / O; // 4096
  const int M = in_sizes[0] / K; // 8192

  const size_t wqB = (size_t)O * K;       // i8 W'
  const size_t xqB = (size_t)M * K;       // i8 x
  const size_t need = wqB + xqB + (size_t)(O + M) * 4 + 256;

  if (ws_size >= need) {
    signed char* Wq = (signed char*)d_ws;
    signed char* Xq = (signed char*)d_ws + wqB;
    float* sw = (float*)((char*)d_ws + wqB + xqB);
    float* sx = sw + O;
    quant_prep<<<O + M, 256, 0, stream>>>(W, Wq, sw, x, Xq, sx, O, K);
    dim3 grid((M / BM2) * (O / BN2)); // 64*16 = 1024, %8 == 0
    gemm_i8_2blk<<<grid, 512, 0, stream>>>(Xq, Wq, sx, sw, b, out, M, O, K);
  } else {
    unsigned short* Wp = (unsigned short*)d_ws;
    const int wvec = (O * K) / 8;
    fwht_only<<<(wvec + 255) / 256, 256, 0, stream>>>(W, Wp, wvec);
    dim3 grid((M / 128) * (O / 128));
    gemm128_a32<<<grid, 256, 0, stream>>>(x, Wp, b, out, M, O, K);
  }
}

// Round 5
// 203.967 us; speedup vs baseline: 1.0500x; 1.0500x over previous
//
#include <hip/hip_runtime.h>
#include <hip/hip_bf16.h>
#include <stdint.h>

#define AS1 __attribute__((address_space(1)))
#define AS3 __attribute__((address_space(3)))

typedef __attribute__((ext_vector_type(8))) short short8;
typedef __attribute__((ext_vector_type(4))) float f32x4;
typedef __attribute__((ext_vector_type(4))) int i32x4;

__device__ __forceinline__ unsigned short f2bf(float f) {
  return __builtin_bit_cast(unsigned short, __float2bfloat16(f));
}

// ---------------------------------------------------------------------------
// Kernel 1 (fused quant prep): one block per matrix row.
// Blocks [0, wrows): FWHT-128 on W row (fp32, in-register) -> row absmax ->
//   i8 quantize -> Wq, s_w[row].
// Blocks [wrows, ...): x row absmax -> i8 quantize -> Xq, s_x[row].
// ---------------------------------------------------------------------------
__global__ __launch_bounds__(256) void quant_prep(const float* __restrict__ W,
                                                  signed char* __restrict__ Wq,
                                                  float* __restrict__ sw,
                                                  const float* __restrict__ x,
                                                  signed char* __restrict__ Xq,
                                                  float* __restrict__ sx,
                                                  int wrows, int Kd) {
  __shared__ float red[4];
  const int bid = blockIdx.x;
  const int tid = threadIdx.x;
  const bool isW = bid < wrows;
  const int row = isW ? bid : bid - wrows;
  const float* src = (isW ? W : x) + (size_t)row * Kd + tid * 16;

  float v[16];
  {
    float4 f0 = ((const float4*)src)[0];
    float4 f1 = ((const float4*)src)[1];
    float4 f2 = ((const float4*)src)[2];
    float4 f3 = ((const float4*)src)[3];
    v[0] = f0.x; v[1] = f0.y; v[2] = f0.z; v[3] = f0.w;
    v[4] = f1.x; v[5] = f1.y; v[6] = f1.z; v[7] = f1.w;
    v[8] = f2.x; v[9] = f2.y; v[10] = f2.z; v[11] = f2.w;
    v[12] = f3.x; v[13] = f3.y; v[14] = f3.z; v[15] = f3.w;
  }

  if (isW) {
#pragma unroll
    for (int m = 1; m <= 8; m <<= 1) {
#pragma unroll
      for (int j = 0; j < 16; ++j) {
        if ((j & m) == 0) {
          float lo = v[j], hi = v[j + m];
          v[j] = lo + hi;
          v[j + m] = lo - hi;
        }
      }
    }
    const int g = tid & 7;
#pragma unroll
    for (int m = 1; m <= 4; m <<= 1) {
#pragma unroll
      for (int j = 0; j < 16; ++j) {
        float p = __shfl_xor(v[j], m, 64);
        v[j] = (g & m) ? (p - v[j]) : (v[j] + p);
      }
    }
    const float s = 0.08838834764831845f; // 1/sqrt(128)
#pragma unroll
    for (int j = 0; j < 16; ++j) v[j] *= s;
  }

  float am = 0.f;
#pragma unroll
  for (int j = 0; j < 16; ++j) am = fmaxf(am, fabsf(v[j]));
#pragma unroll
  for (int m = 1; m < 64; m <<= 1) am = fmaxf(am, __shfl_xor(am, m, 64));
  if ((tid & 63) == 0) red[tid >> 6] = am;
  __syncthreads();
  am = fmaxf(fmaxf(red[0], red[1]), fmaxf(red[2], red[3]));

  const float inv = (am > 1e-30f) ? (127.0f / am) : 0.f;
  union { uint4 u; signed char c[16]; } pk;
#pragma unroll
  for (int j = 0; j < 16; ++j) {
    float q = __builtin_rintf(v[j] * inv);
    q = fminf(127.f, fmaxf(-127.f, q));
    pk.c[j] = (signed char)(int)q;
  }
  signed char* dst = (isW ? Wq : Xq) + (size_t)row * Kd + tid * 16;
  *(uint4*)dst = pk.u;
  if (tid == 0) (isW ? sw : sx)[row] = am / 127.0f;
}

// ---------------------------------------------------------------------------
__device__ __forceinline__ void gload16(const void* g, void* l) {
  __builtin_amdgcn_global_load_lds((const AS1 unsigned int*)g,
                                   (AS3 unsigned int*)l, 16, 0, 0);
}

// ---------------------------------------------------------------------------
// Kernel 2: i8 GEMM, big-wave ILP build (AITER-style in-wave pipeline).
//
// R1-R3 post-mortem: every 2-waves/SIMD config (wave-tile <= 128x64) fills
// the 256-reg budget exactly (128 VGPR + 128 acc) -> NO headroom to double-
// buffer operands -> every schedule needs a wait between ds_reads and their
// MFMAs -> LDS (~1540 cyc/phase, CU-serial) and MFMA (~1310 cyc/SIMD)
// serialize. Barrier reshuffles (R2,R3) and occupancy (R1) all null/regress:
// the convoy is register-forced, not schedule-forced.
//
// Escape: 1 wave/SIMD (512-reg budget), wave-tile 128x128 (acc[8][8]=256
// regs) + TWO operand sets (128 regs) -> in-wave software pipeline:
//   phase t: {ds_read tile t+1 -> other set; stage tile t+3; lgkmcnt(15)
//             [= tile t's reads done; 4-bit field caps at 15 -- R4 fix;
//             DS is in-order per wave so <=15 outstanding => all 16 of the
//             previous phase's reads drained]; 64x MFMA on tile t;
//             vmcnt(8) [= tile t+1 landed]; barrier}
// The DS pipe drains the 16 reads + 8 LDS-writes (~1150 cyc/CU) UNDER the
// 64-MFMA burst (1306 cyc/SIMD). Ops/LDS-byte: 85 -> 128.
//
// Block 256x256, 4 waves (2x2 of 128x128), 256 thr, BK=64. 4-slot LDS ring
// (32 KB/slot, 128 KB): slot holding tile t is restaged in phase t+3; its
// reads (issued phase t-1) are confirmed by phase t's lgkmcnt wait in every
// wave before the end-of-phase-t barrier -> one-barrier-safe with 4 slots.
// vmcnt ledger: 8 loads/phase, steady outstanding 16; vmcnt(8) drains
// exactly tile t+1; never 0 in the loop.
// Same XOR involution on pre-swizzled global sources AND ds_read offsets
// (rule #21). Rule #18 sched_barrier(0) after every counted wait; rule #20:
// operand sets NAMED (avA/avB), loop unrolled 4 phases -> const slot ptrs.
// Dequant epilogue: out = sx[m]*sw[n]*acc + b[n] (integer accum is exact).
// ---------------------------------------------------------------------------
#define BM3 256
#define BN3 256
#define SLOT3 32768 // A plane 16384 B (256 rows x 64) + B plane 16384 B

__global__ __launch_bounds__(256, 1) void gemm_i8_bigwave(const signed char* __restrict__ Xq,
                                                          const signed char* __restrict__ Wq,
                                                          const float* __restrict__ sx,
                                                          const float* __restrict__ sw,
                                                          const float* __restrict__ bias,
                                                          float* __restrict__ out,
                                                          int M, int N, int K) {
  __shared__ __align__(16) char lds[4 * SLOT3];

  const int tid = threadIdx.x; // 0..255
  const int lane = tid & 63;
  const int wid = tid >> 6; // 0..3
  const int wm = wid >> 1;  // 0..1  (128-row strip)
  const int wn = wid & 1;   // 0..1  (128-col strip)

  // XCD bijective swizzle (gridDim.x = 512, multiple of 8)
  const int nwg = gridDim.x;
  const int cpx = nwg >> 3;
  const int swzb = (blockIdx.x & 7) * cpx + (blockIdx.x >> 3);
  const int nbn = N / BN3;
  const int m0 = (swzb / nbn) * BM3;
  const int n0 = (swzb % nbn) * BN3;
  const size_t Kb = (size_t)K; // 1 byte/elem

  // ---- stage source pointers: pre-swizzled global (rule #21) ----
  // LDS linear offset d (plane-relative) receives data of logical offset
  // l = d ^ (((d>>7)&3)<<4); reads use the same involution -> consistent.
  const char* sAg[4];
  const char* sBg[4];
#pragma unroll
  for (int j = 0; j < 4; ++j) {
    const int d = tid * 16 + j * 4096; // plane-relative [0, 16384)
    const int l = d ^ (((d >> 7) & 3) << 4);
    sAg[j] = (const char*)Xq + (size_t)(m0 + (l >> 6)) * Kb + (l & 63);
    sBg[j] = (const char*)Wq + (size_t)(n0 + (l >> 6)) * Kb + (l & 63);
  }

  // ---- swizzled in-plane ds_read offsets (same involution) ----
  const int q = lane >> 4;  // k-chunk 0..3 (16 B each = 16 i8)
  const int fr = lane & 15; // frag row
  int oA[8], oB[8];
#pragma unroll
  for (int mi = 0; mi < 8; ++mi) {
    int row = wm * 128 + mi * 16 + fr; // 0..255
    int byt = row * 64 + q * 16;
    oA[mi] = byt ^ (((byt >> 7) & 3) << 4);
  }
#pragma unroll
  for (int ni = 0; ni < 8; ++ni) {
    int row = wn * 128 + ni * 16 + fr; // 0..255
    int byt = row * 64 + q * 16;
    oB[ni] = byt ^ (((byt >> 7) & 3) << 4);
  }

  i32x4 acc[8][8];
#pragma unroll
  for (int i = 0; i < 8; ++i)
#pragma unroll
    for (int j = 0; j < 8; ++j) acc[i][j] = (i32x4){0, 0, 0, 0};

  char* const L0 = lds;
  char* const L1 = lds + SLOT3;
  char* const L2 = lds + 2 * SLOT3;
  char* const L3 = lds + 3 * SLOT3;

#define STAGE8(SL_, ko_)                                                     \
  do {                                                                       \
    _Pragma("unroll") for (int j = 0; j < 4; ++j)                            \
        gload16(sAg[j] + (ko_), (SL_) + tid * 16 + j * 4096);                \
    _Pragma("unroll") for (int j = 0; j < 4; ++j)                            \
        gload16(sBg[j] + (ko_), (SL_) + 16384 + tid * 16 + j * 4096);        \
  } while (0)

#define READ16(SL_, av_, bv_)                                                \
  do {                                                                       \
    _Pragma("unroll") for (int mi = 0; mi < 8; ++mi)                         \
        av_[mi] = *(const i32x4*)((SL_) + oA[mi]);                           \
    _Pragma("unroll") for (int ni = 0; ni < 8; ++ni)                         \
        bv_[ni] = *(const i32x4*)((SL_) + 16384 + oB[ni]);                   \
  } while (0)

#define MFMA64(av_, bv_)                                                     \
  do {                                                                       \
    _Pragma("unroll") for (int mi = 0; mi < 8; ++mi)                         \
        _Pragma("unroll") for (int ni = 0; ni < 8; ++ni)                     \
            acc[mi][ni] = __builtin_amdgcn_mfma_i32_16x16x64_i8(             \
                av_[mi], bv_[ni], acc[mi][ni], 0, 0, 0);                     \
  } while (0)

  // Phase t: read tile t+1 from RS=slot[(t+1)&3] into nxt set; stage tile
  // t+3 into SS=slot[(t+3)&3]; lgkm(15) confirms cur set (tile t); MFMA cur;
  // vmcnt(8) confirms tile t+1 landed; barrier publishes it + fences restage.
#define PHASE(avC_, bvC_, avN_, bvN_, RS_, SS_)                              \
  do {                                                                       \
    READ16(RS_, avN_, bvN_);                                                 \
    STAGE8(SS_, koff);                                                       \
    koff += 64;                                                              \
    if (koff >= K) koff -= K; /* ring wrap: dead-slot restage, never read */ \
    asm volatile("s_waitcnt lgkmcnt(15)" ::: "memory");                      \
    __builtin_amdgcn_sched_barrier(0);                                       \
    MFMA64(avC_, bvC_);                                                      \
    __builtin_amdgcn_sched_barrier(0);                                       \
    asm volatile("s_waitcnt vmcnt(8)" ::: "memory");                         \
    __builtin_amdgcn_s_barrier();                                            \
    asm volatile("" ::: "memory");                                           \
  } while (0)

  // ---- prologue: tiles 0,1,2 -> slots 0,1,2; confirm tiles 0,1 ----
  STAGE8(L0, 0);
  STAGE8(L1, 64);
  STAGE8(L2, 128);
  int koff = 192; // K-byte offset of tile 3 (first in-loop stage)
  asm volatile("s_waitcnt vmcnt(8)" ::: "memory"); // tiles 0,1 landed
  __builtin_amdgcn_s_barrier();
  asm volatile("" ::: "memory");

  i32x4 avA[8], bvA[8], avB[8], bvB[8];
  READ16(L0, avA, bvA); // tile 0 -> set A

  // NT = K/64 = 64 tiles; phases t=0..62 in 4-phase-unrolled loop + tail,
  // final tile 63 MFMA'd after the loop.
  for (int it = 0; it < 15; ++it) { // t = 4*it .. 4*it+3  (0..59)
    PHASE(avA, bvA, avB, bvB, L1, L3);
    PHASE(avB, bvB, avA, bvA, L2, L0);
    PHASE(avA, bvA, avB, bvB, L3, L1);
    PHASE(avB, bvB, avA, bvA, L0, L2);
  }
  PHASE(avA, bvA, avB, bvB, L1, L3); // t=60
  PHASE(avB, bvB, avA, bvA, L2, L0); // t=61
  PHASE(avA, bvA, avB, bvB, L3, L1); // t=62: reads tile 63 -> set B
  asm volatile("s_waitcnt lgkmcnt(0)" ::: "memory");
  __builtin_amdgcn_sched_barrier(0);
  MFMA64(avB, bvB); // t=63 (final, no reads/stage)
  asm volatile("s_waitcnt vmcnt(0)" ::: "memory"); // drain wrapped stages

  // ---- epilogue: C/D col=lane&15, row=(lane>>4)*4+r (dtype-independent);
  // dequant out = sx[row]*sw[col]*acc + b[col], fp32 store.
  const int orow = m0 + wm * 128;
  const int ocol = n0 + wn * 128;
  const int rsub = q << 2;
  float swv[8], bcv[8];
#pragma unroll
  for (int ni = 0; ni < 8; ++ni) {
    const int col = ocol + ni * 16 + fr;
    swv[ni] = sw[col];
    bcv[ni] = bias[col];
  }
#pragma unroll
  for (int mi = 0; mi < 8; ++mi) {
    const int rbase = orow + mi * 16 + rsub;
#pragma unroll
    for (int r = 0; r < 4; ++r) {
      const int row = rbase + r;
      const float sxr = sx[row];
      float* orow_p = out + (size_t)row * N;
#pragma unroll
      for (int ni = 0; ni < 8; ++ni) {
        const int col = ocol + ni * 16 + fr;
        orow_p[col] = (float)acc[mi][ni][r] * (sxr * swv[ni]) + bcv[ni];
      }
    }
  }
#undef STAGE8
#undef READ16
#undef MFMA64
#undef PHASE
}

// ---------------------------------------------------------------------------
// Fallback (small workspace): bf16 path — standalone FWHT + 128^2 GEMM.
// ---------------------------------------------------------------------------
__global__ __launch_bounds__(256) void fwht_only(const float* __restrict__ W,
                                                 unsigned short* __restrict__ Wp,
                                                 int total_vec) {
  int t = blockIdx.x * blockDim.x + threadIdx.x;
  if (t >= total_vec) return;
  float4 r0 = ((const float4*)W)[2 * t];
  float4 r1 = ((const float4*)W)[2 * t + 1];
  float v[8] = {r0.x, r0.y, r0.z, r0.w, r1.x, r1.y, r1.z, r1.w};
#pragma unroll
  for (int m = 1; m <= 4; m <<= 1) {
#pragma unroll
    for (int j = 0; j < 8; ++j) {
      if ((j & m) == 0) {
        float lo = v[j], hi = v[j + m];
        v[j] = lo + hi;
        v[j + m] = lo - hi;
      }
    }
  }
  const int g = t & 15;
#pragma unroll
  for (int m = 1; m <= 8; m <<= 1) {
#pragma unroll
    for (int j = 0; j < 8; ++j) {
      float p = __shfl_xor(v[j], m, 64);
      v[j] = (g & m) ? (p - v[j]) : (v[j] + p);
    }
  }
  const float s = 0.08838834764831845f;
  uint4 outv;
  unsigned short* ou = (unsigned short*)&outv;
#pragma unroll
  for (int j = 0; j < 8; ++j) ou[j] = f2bf(v[j] * s);
  ((uint4*)Wp)[t] = outv;
}

__global__ __launch_bounds__(256) void gemm128_a32(const float* __restrict__ X,
                                                   const unsigned short* __restrict__ Wp,
                                                   const float* __restrict__ bias,
                                                   float* __restrict__ out,
                                                   int M, int N, int K) {
  __shared__ __align__(16) unsigned short lA[128 * 32];
  __shared__ __align__(16) unsigned short lB[128 * 32];
  const int tid = threadIdx.x;
  const int lane = tid & 63;
  const int wid = tid >> 6;
  const int wr = wid >> 1, wc = wid & 1;
  const int nbn = N / 128;
  const int bm = blockIdx.x / nbn, bn = blockIdx.x % nbn;
  const int m0 = bm * 128, n0 = bn * 128;
  f32x4 acc[4][4];
#pragma unroll
  for (int i = 0; i < 4; ++i)
#pragma unroll
    for (int j = 0; j < 4; ++j) acc[i][j] = (f32x4){0.f, 0.f, 0.f, 0.f};
  const size_t Kb = (size_t)K * 2;
  const int off0 = tid * 16, off1 = off0 + 4096;
  const int r0 = off0 >> 6, c0 = off0 & 63;
  const int r1 = off1 >> 6, c1 = off1 & 63;
  const char* Bg0 = (const char*)Wp + (size_t)(n0 + r0) * Kb + c0;
  const char* Bg1 = (const char*)Wp + (size_t)(n0 + r1) * Kb + c1;
  char* lB0 = (char*)lB + off0;
  char* lB1 = (char*)lB + off1;
  const int arow = tid >> 1;
  const int acol = (tid & 1) * 16;
  const float* Af = X + (size_t)(m0 + arow) * K + acol;
  unsigned short* lAw = &lA[arow * 32 + acol];
  const int fr = lane & 15;
  const int kc = (lane >> 4) << 3;
  const unsigned short* pA = &lA[(wr * 64 + fr) * 32 + kc];
  const unsigned short* pB = &lB[(wc * 64 + fr) * 32 + kc];
  for (int k0 = 0; k0 < K; k0 += 32) {
    const int kb = k0 << 1;
    gload16(Bg0 + kb, lB0);
    gload16(Bg1 + kb, lB1);
    const float* src = Af + k0;
    float4 f0 = *(const float4*)(src + 0);
    float4 f1 = *(const float4*)(src + 4);
    float4 f2 = *(const float4*)(src + 8);
    float4 f3 = *(const float4*)(src + 12);
    union { uint4 u[2]; unsigned short s[16]; } pk;
    float vv[16] = {f0.x, f0.y, f0.z, f0.w, f1.x, f1.y, f1.z, f1.w,
                    f2.x, f2.y, f2.z, f2.w, f3.x, f3.y, f3.z, f3.w};
#pragma unroll
    for (int j = 0; j < 16; ++j) pk.s[j] = f2bf(vv[j]);
    ((uint4*)lAw)[0] = pk.u[0];
    ((uint4*)(lAw + 8))[0] = pk.u[1];
    __syncthreads();
    short8 af[4], bfr[4];
#pragma unroll
    for (int mi = 0; mi < 4; ++mi) af[mi] = *(const short8*)(pA + mi * 16 * 32);
#pragma unroll
    for (int ni = 0; ni < 4; ++ni) bfr[ni] = *(const short8*)(pB + ni * 16 * 32);
#pragma unroll
    for (int mi = 0; mi < 4; ++mi)
#pragma unroll
      for (int ni = 0; ni < 4; ++ni)
        acc[mi][ni] = __builtin_amdgcn_mfma_f32_16x16x32_bf16(af[mi], bfr[ni],
                                                              acc[mi][ni], 0, 0, 0);
    __syncthreads();
  }
  const int orow0 = m0 + wr * 64;
  const int ocol0 = n0 + wc * 64;
  const int rsub = (lane >> 4) << 2;
#pragma unroll
  for (int ni = 0; ni < 4; ++ni) {
    const int col = ocol0 + ni * 16 + fr;
    const float bc = bias[col];
#pragma unroll
    for (int mi = 0; mi < 4; ++mi)
#pragma unroll
      for (int r = 0; r < 4; ++r)
        out[(size_t)(orow0 + mi * 16 + rsub + r) * N + col] = acc[mi][ni][r] + bc;
  }
}

// ---------------------------------------------------------------------------
extern "C" void kernel_launch(void* const* d_in, const int* in_sizes, int n_in,
                              void* d_out, int out_size, void* d_ws, size_t ws_size,
                              hipStream_t stream) {
  const float* x = (const float*)d_in[0];
  const float* W = (const float*)d_in[1];
  const float* b = (const float*)d_in[2];
  float* out = (float*)d_out;

  const int O = in_sizes[2];     // 4096
  const int K = in_sizes[1] / O; // 4096
  const int M = in_sizes[0] / K; // 8192

  const size_t wqB = (size_t)O * K;       // i8 W'
  const size_t xqB = (size_t)M * K;       // i8 x
  const size_t need = wqB + xqB + (size_t)(O + M) * 4 + 256;

  if (ws_size >= need) {
    signed char* Wq = (signed char*)d_ws;
    signed char* Xq = (signed char*)d_ws + wqB;
    float* sw = (float*)((char*)d_ws + wqB + xqB);
    float* sx = sw + O;
    quant_prep<<<O + M, 256, 0, stream>>>(W, Wq, sw, x, Xq, sx, O, K);
    dim3 grid((M / BM3) * (O / BN3)); // 32*16 = 512, %8 == 0
    gemm_i8_bigwave<<<grid, 256, 0, stream>>>(Xq, Wq, sx, sw, b, out, M, O, K);
  } else {
    unsigned short* Wp = (unsigned short*)d_ws;
    const int wvec = (O * K) / 8;
    fwht_only<<<(wvec + 255) / 256, 256, 0, stream>>>(W, Wp, wvec);
    dim3 grid((M / 128) * (O / 128));
    gemm128_a32<<<grid, 256, 0, stream>>>(x, Wp, b, out, M, O, K);
  }
}